// Round 5
// baseline (599.985 us; speedup 1.0000x reference)
//
#include <hip/hip_runtime.h>

// Problem dims
#define B_  4096
#define T_  128
#define NL  256
#define NS  64
#define NO  32
#define V_  64
#define RB  16            // rows per block
#define NBLK (B_ / RB)    // 256 blocks

typedef __bf16 bf16;
typedef bf16  bf16x8 __attribute__((ext_vector_type(8)));
typedef bf16  bf16x4 __attribute__((ext_vector_type(4)));
typedef float f32x4  __attribute__((ext_vector_type(4)));

#define MF(a, b, c) __builtin_amdgcn_mfma_f32_16x16x32_bf16(a, b, c, 0, 0, 0)

// lgkm-only barrier: block communication is exclusively via LDS.
#define LGKM_BARRIER() asm volatile("s_waitcnt lgkmcnt(0)\n\ts_barrier" ::: "memory")

// Manual weight load, flat-global form (threadIdx-derived bases are not
// provably wave-uniform -> no SGPR saddr). asm volatile keeps issue order =
// consumption order, which makes the counted vmcnt(16) waits exact.
#define GLOAD(dst, ptr, off) \
    asm volatile("global_load_dwordx4 %0, %1, off offset:" #off \
                 : "=v"(dst) : "v"(ptr))

// ---------------------------------------------------------------------------
// Split fp32 weights -> bf16 hi/lo planes in MFMA A-fragment order.
// ---------------------------------------------------------------------------
template <int TSHIFT>
__global__ void split_w_frag(const float* __restrict__ src,
                             bf16* __restrict__ hi, bf16* __restrict__ lo,
                             int total4) {
    int t4 = blockIdx.x * blockDim.x + threadIdx.x;
    if (t4 >= total4) return;
    const int jb   = (t4 & 1) * 4;
    const int L    = (t4 >> 1) & 63;
    const int ks   = (t4 >> 7) & 7;
    const int rest = t4 >> 10;
    const int t    = rest & ((1 << TSHIFT) - 1);
    const int s    = rest >> TSHIFT;
    const int row  = ((s << TSHIFT) + t) * 16 + (L & 15);
    const int k    = ks * 32 + (L >> 4) * 8 + jb;
    const float4 v = *(const float4*)(src + (size_t)row * NL + k);
    float vv[4] = {v.x, v.y, v.z, v.w};
    bf16x4 h, l;
#pragma unroll
    for (int e = 0; e < 4; e++) {
        bf16 hh = (bf16)vv[e];
        h[e] = hh;
        l[e] = (bf16)(vv[e] - (float)hh);
    }
    *(bf16x4*)(hi + (size_t)t4 * 4) = h;
    *(bf16x4*)(lo + (size_t)t4 * 4) = l;
}

// inv[s][v] = last j with out_idx[s][j]==v, else -1 (numpy last-dup-wins)
__global__ void inv_kernel(const int* __restrict__ out_idx, int* __restrict__ inv) {
    int t = blockIdx.x * blockDim.x + threadIdx.x;
    if (t >= NS * V_) return;
    int s = t >> 6, v = t & 63;
    int jf = -1;
#pragma unroll
    for (int j = 0; j < NO; j++)
        if (out_idx[(s << 5) | j] == v) jf = j;
    inv[t] = jf;
}

__device__ __forceinline__ float fast_tanh(float z) {
    float e = __expf(2.0f * z);
    return 1.0f - 2.0f / (e + 1.0f);
}

// x fragment-order address for element (batch row n, k = t*16 + q*4):
__device__ __forceinline__ int xaddr(int t, int q, int n) {
    return ((t >> 1) * 512) + (((t & 1) * 2 + (q >> 1)) * 128) + n * 8 + (q & 1) * 4;
}

// ---------------------------------------------------------------------------
// Persistent per-block recurrence, 256 blocks x 16 waves, 1 block/CU.
// Weight pipeline: 18 asm global_load_dwordx4 per wave per step, each pair
// reissued right after its consumption -> issue-to-use = one full step.
// Consumption paced by s_waitcnt vmcnt(16) + sched_barrier(0).
// FIFO (steady state): queue/step = 16 W1 + 2 W2 + 1 out-store = 19 ops;
// at slice-ks wait, younger-than-target = 17 -> vmcnt(16) retires the pair
// (1-op conservative; vmcnt drains oldest-first).
// x-fragment LDS reads are 3-slot software-pipelined (issue slice ks+2
// before slice ks's MFMAs) so sched_barrier(0) doesn't expose LDS latency.
// Softmax spread over all 16 waves (wave w <-> row w).
// ---------------------------------------------------------------------------
__launch_bounds__(1024, 4)
__global__ void lalr_main(const float* __restrict__ latent0,
                          const float* __restrict__ b1,
                          const float* __restrict__ b2,
                          const int*   __restrict__ state_seq,
                          const int*   __restrict__ inv,
                          const bf16*  __restrict__ W1h, const bf16* __restrict__ W1l,
                          const bf16*  __restrict__ W2h, const bf16* __restrict__ W2l,
                          float* __restrict__ out) {
    __shared__ bf16  xh[2][4096];        // 16 KB
    __shared__ bf16  xl[2][4096];        // 16 KB
    __shared__ float Sp[2][8][16][36];   // 36 KB
    __shared__ float b1s[NS * NL];       // 64 KB
    __shared__ float b2s[NS * NO];       //  8 KB
    __shared__ int   invs[NS * V_];      // 16 KB
    __shared__ int   sseq[T_];           // 0.5 KB   total 160,256 B <= 160 KiB

    const int tid  = threadIdx.x;
    const int wave = tid >> 6;           // 0..15
    const int lane = tid & 63;
    const int n    = lane & 15;          // batch row
    const int q    = lane >> 4;          // quad
    const int r0   = blockIdx.x * RB;
    const int t2   = wave & 1;           // GEMM2 col-tile
    const int ks2  = wave >> 1;          // GEMM2 K-slice

    // ---- stage uniforms into LDS (prologue-only global traffic) ----
    for (int k = tid; k < NS * NL / 4; k += 1024)
        ((float4*)b1s)[k] = ((const float4*)b1)[k];
    if (tid < NS * NO / 4) ((float4*)b2s)[tid] = ((const float4*)b2)[tid];
    if (tid < NS * V_ / 4) ((int4*)invs)[tid] = ((const int4*)inv)[tid];
    if (tid < T_) sseq[tid] = state_seq[tid];

    // ---- init: latent0 -> x[0] fragments ----
    {
        float4 v = *(const float4*)(latent0 + (size_t)(r0 + n) * NL + wave * 16 + q * 4);
        float vv[4] = {v.x, v.y, v.z, v.w};
        bf16x4 hv, lv;
#pragma unroll
        for (int e = 0; e < 4; e++) {
            bf16 hh = (bf16)vv[e];
            hv[e] = hh;
            lv[e] = (bf16)(vv[e] - (float)hh);
        }
        const int a = xaddr(wave, q, n);
        *(bf16x4*)(&xh[0][a]) = hv;
        *(bf16x4*)(&xl[0][a]) = lv;
    }

    int s0 = state_seq[0], s1 = -1, s2 = -1;

    // 18 loop-carried weight fragment registers (live in unified VGPR/AGPR file).
    bf16x8 pwh0, pwh1, pwh2, pwh3, pwh4, pwh5, pwh6, pwh7;
    bf16x8 pwl0, pwl1, pwl2, pwl3, pwl4, pwl5, pwl6, pwl7;
    bf16x8 w2h2, w2l2;

    const size_t wfrag = (size_t)wave * 8 * 512 + lane * 8;  // per-wave/lane W1 offset

    // Prologue issue of L_0 in exact consumption order (18 ops).
    {
        const bf16* h0 = W1h + (size_t)s0 * 16 * 8 * 512 + wfrag;
        const bf16* l0 = W1l + (size_t)s0 * 16 * 8 * 512 + wfrag;
        const bf16* h4 = h0 + 4 * 512;
        const bf16* l4 = l0 + 4 * 512;
        GLOAD(pwh0, h0, 0);    GLOAD(pwl0, l0, 0);
        GLOAD(pwh1, h0, 1024); GLOAD(pwl1, l0, 1024);
        GLOAD(pwh2, h0, 2048); GLOAD(pwl2, l0, 2048);
        GLOAD(pwh3, h0, 3072); GLOAD(pwl3, l0, 3072);
        GLOAD(pwh4, h4, 0);    GLOAD(pwl4, l4, 0);
        GLOAD(pwh5, h4, 1024); GLOAD(pwl5, l4, 1024);
        GLOAD(pwh6, h4, 2048); GLOAD(pwl6, l4, 2048);
        GLOAD(pwh7, h4, 3072); GLOAD(pwl7, l4, 3072);
        const bf16* c2h = W2h + (size_t)((s0 * 2 + t2) * 8 + ks2) * 512 + lane * 8;
        const bf16* c2l = W2l + (size_t)((s0 * 2 + t2) * 8 + ks2) * 512 + lane * 8;
        GLOAD(w2h2, c2h, 0);   GLOAD(w2l2, c2l, 0);   // placeholder (iter-0 GEMM2 skipped)
    }

    LGKM_BARRIER();      // x[0]/staging visible; weight loads stay in flight

#define XRD(dst, arr, ks) dst = *(const bf16x8*)(&arr[cur][(ks) * 512 + lane * 8])

// One GEMM1 slice: prefetch x for slice ks+2, counted wait, fence, 3 MFMA,
// reissue weight pair. __VA_ARGS__ = the prefetch statements.
#define G1S(ks, A, B, PH, PL, off, ...)                                     \
    {                                                                       \
        __VA_ARGS__                                                         \
        asm volatile("s_waitcnt vmcnt(16)" ::: "memory");                   \
        __builtin_amdgcn_sched_barrier(0);                                  \
        acc1 = MF(pwh##ks, A, acc1);                                        \
        acc1 = MF(pwl##ks, A, acc1);                                        \
        acc1 = MF(pwh##ks, B, acc1);                                        \
        GLOAD(pwh##ks, PH, off);                                            \
        GLOAD(pwl##ks, PL, off);                                            \
    }

    for (int i = 0; i <= T_ + 1; i++) {
        const int ib  = i & 1;
        const int cur = ib;

        // next-step W1 base pointers (dummy state 0 in tail keeps FIFO shape)
        const int ns0 = (i + 1 < T_) ? sseq[i + 1] : -1;
        const int ls  = (ns0 >= 0) ? ns0 : 0;
        const bf16* nh0 = W1h + (size_t)ls * 16 * 8 * 512 + wfrag;
        const bf16* nl0 = W1l + (size_t)ls * 16 * 8 * 512 + wfrag;
        const bf16* nh4 = nh0 + 4 * 512;
        const bf16* nl4 = nl0 + 4 * 512;

        bf16x8 g2a, g2b;   // GEMM2 x fragments (prefetched in GEMM1 tail)

        // ---- GEMM1 (state s0): full K=256, vmcnt-paced, 3-slot x pipeline ----
        f32x4 acc1;
        if (s0 >= 0) {
            acc1 = (f32x4){0.f, 0.f, 0.f, 0.f};
            bf16x8 a0, b0, a1, b1v, a2, b2v;
            XRD(a0, xh, 0); XRD(b0, xl, 0);
            XRD(a1, xh, 1); XRD(b1v, xl, 1);
            G1S(0, a0, b0,  nh0, nl0, 0,    XRD(a2, xh, 2); XRD(b2v, xl, 2);)
            G1S(1, a1, b1v, nh0, nl0, 1024, XRD(a0, xh, 3); XRD(b0, xl, 3);)
            G1S(2, a2, b2v, nh0, nl0, 2048, XRD(a1, xh, 4); XRD(b1v, xl, 4);)
            G1S(3, a0, b0,  nh0, nl0, 3072, XRD(a2, xh, 5); XRD(b2v, xl, 5);)
            G1S(4, a1, b1v, nh4, nl4, 0,    XRD(a0, xh, 6); XRD(b0, xl, 6);)
            G1S(5, a2, b2v, nh4, nl4, 1024, XRD(a1, xh, 7); XRD(b1v, xl, 7);)
            G1S(6, a0, b0,  nh4, nl4, 2048, XRD(g2a, xh, ks2); XRD(g2b, xl, ks2);)
            G1S(7, a1, b1v, nh4, nl4, 3072, )
        }

        // ---- GEMM2 (state s1): task (t2, ks2) ----
        if (s1 >= 0) {
            if (s0 < 0) { XRD(g2a, xh, ks2); XRD(g2b, xl, ks2); }
            if (s0 >= 0) {
                asm volatile("s_waitcnt vmcnt(16)" ::: "memory");
            } else {
                // tail: GEMM1 skipped -> 16 dummy W1 loads unconsumed ahead
                asm volatile("s_waitcnt vmcnt(0)" ::: "memory");
            }
            __builtin_amdgcn_sched_barrier(0);
            f32x4 a2acc = (f32x4){0.f, 0.f, 0.f, 0.f};
            a2acc = MF(w2h2, g2a, a2acc);
            a2acc = MF(w2l2, g2a, a2acc);
            a2acc = MF(w2h2, g2b, a2acc);
            if (ks2 == 0) {
                float4 bb = *(const float4*)(&b2s[s1 * NO + t2 * 16 + q * 4]);
                a2acc[0] += bb.x; a2acc[1] += bb.y; a2acc[2] += bb.z; a2acc[3] += bb.w;
            }
            *(f32x4*)(&Sp[ib][ks2][n][t2 * 16 + q * 4]) = a2acc;
        }
        if (s0 >= 0) {   // reissue W2 pair for next iteration (state = current s0)
            const bf16* n2h = W2h + (size_t)((s0 * 2 + t2) * 8 + ks2) * 512 + lane * 8;
            const bf16* n2l = W2l + (size_t)((s0 * 2 + t2) * 8 + ks2) * 512 + lane * 8;
            GLOAD(w2h2, n2h, 0);
            GLOAD(w2l2, n2l, 0);
        }

        // ---- softmax + shfl-scatter + store for step i-2: wave w <-> row w ----
        if (s2 >= 0) {
            const int pb = (i - 1) & 1;
            const int c  = lane & 31;        // col (lanes 32..63 mirror 0..31)
            float v = 0.f;
#pragma unroll
            for (int w8 = 0; w8 < 8; w8++) v += Sp[pb][w8][wave][c];
            float m = v;
#pragma unroll
            for (int d = 1; d < 32; d <<= 1) m = fmaxf(m, __shfl_xor(m, d));
            float e = __expf(v - m);
            float su = e;
#pragma unroll
            for (int d = 1; d < 32; d <<= 1) su += __shfl_xor(su, d);
            float p = e / su;                // mirrored in both lane halves
            int iv = invs[s2 * V_ + lane];   // lane = output token v
            float g = __shfl(p, iv & 31);
            out[((size_t)(r0 + wave) * T_ + (i - 2)) * V_ + lane] = (iv < 0) ? 0.f : g;
        }

        // ---- tanh + hi/lo split -> x[cur^1] ----
        if (s0 >= 0) {
            float4 bb = *(const float4*)(&b1s[s0 * NL + wave * 16 + q * 4]);
            float bv[4] = {bb.x, bb.y, bb.z, bb.w};
            bf16x4 hv, lv;
#pragma unroll
            for (int e = 0; e < 4; e++) {
                float h = fast_tanh(acc1[e] + bv[e]);
                bf16 hh = (bf16)h;
                hv[e] = hh;
                lv[e] = (bf16)(h - (float)hh);
            }
            const int a = xaddr(wave, q, n);
            *(bf16x4*)(&xh[cur ^ 1][a]) = hv;
            *(bf16x4*)(&xl[cur ^ 1][a]) = lv;
        }

        s2 = s1; s1 = s0; s0 = ns0;
        LGKM_BARRIER();
    }
#undef G1S
#undef XRD
}

extern "C" void kernel_launch(void* const* d_in, const int* in_sizes, int n_in,
                              void* d_out, int out_size, void* d_ws, size_t ws_size,
                              hipStream_t stream) {
    const float* latent0   = (const float*)d_in[0];
    const float* W1        = (const float*)d_in[1];
    const float* b1        = (const float*)d_in[2];
    const float* W2        = (const float*)d_in[3];
    const float* b2        = (const float*)d_in[4];
    const int*   state_seq = (const int*)d_in[5];
    const int*   out_idx   = (const int*)d_in[6];
    float* out = (float*)d_out;

    bf16* W1h = (bf16*)d_ws;
    bf16* W1l = W1h + (size_t)NS * NL * NL;
    bf16* W2h = W1l + (size_t)NS * NL * NL;
    bf16* W2l = W2h + (size_t)NS * NO * NL;
    int*  inv = (int*)(W2l + (size_t)NS * NO * NL);

    const int n4_w1 = NS * NL * NL / 4;   // 1,048,576
    const int n4_w2 = NS * NO * NL / 4;   // 131,072
    split_w_frag<4><<<n4_w1 / 256, 256, 0, stream>>>(W1, W1h, W1l, n4_w1);
    split_w_frag<1><<<n4_w2 / 256, 256, 0, stream>>>(W2, W2h, W2l, n4_w2);
    inv_kernel<<<(NS * V_ + 255) / 256, 256, 0, stream>>>(out_idx, inv);

    lalr_main<<<NBLK, 1024, 0, stream>>>(latent0, b1, b2, state_seq, inv,
                                         W1h, W1l, W2h, W2l, out);
}

// Round 6
// 535.587 us; speedup vs baseline: 1.1202x; 1.1202x over previous
//
#include <hip/hip_runtime.h>

// Problem dims
#define B_  4096
#define T_  128
#define NL  256
#define NS  64
#define NO  32
#define V_  64
#define RB  16            // rows per block
#define NBLK (B_ / RB)    // 256 blocks

typedef __bf16 bf16;
typedef bf16  bf16x8 __attribute__((ext_vector_type(8)));
typedef bf16  bf16x4 __attribute__((ext_vector_type(4)));
typedef float f32x4  __attribute__((ext_vector_type(4)));

#define MF(a, b, c) __builtin_amdgcn_mfma_f32_16x16x32_bf16(a, b, c, 0, 0, 0)

// lgkm-only barrier: block communication is exclusively via LDS.
#define LGKM_BARRIER() asm volatile("s_waitcnt lgkmcnt(0)\n\ts_barrier" ::: "memory")

// Manual weight load, flat-global form (threadIdx-derived bases are not
// provably wave-uniform -> no SGPR saddr). asm volatile keeps issue order =
// consumption order, which makes the counted vmcnt(16) waits exact.
#define GLOAD(dst, ptr) \
    asm volatile("global_load_dwordx4 %0, %1, off" : "=v"(dst) : "v"(ptr))

// ---------------------------------------------------------------------------
// Split fp32 weights -> bf16 hi/lo planes in MFMA A-fragment order.
// ---------------------------------------------------------------------------
template <int TSHIFT>
__global__ void split_w_frag(const float* __restrict__ src,
                             bf16* __restrict__ hi, bf16* __restrict__ lo,
                             int total4) {
    int t4 = blockIdx.x * blockDim.x + threadIdx.x;
    if (t4 >= total4) return;
    const int jb   = (t4 & 1) * 4;
    const int L    = (t4 >> 1) & 63;
    const int ks   = (t4 >> 7) & 7;
    const int rest = t4 >> 10;
    const int t    = rest & ((1 << TSHIFT) - 1);
    const int s    = rest >> TSHIFT;
    const int row  = ((s << TSHIFT) + t) * 16 + (L & 15);
    const int k    = ks * 32 + (L >> 4) * 8 + jb;
    const float4 v = *(const float4*)(src + (size_t)row * NL + k);
    float vv[4] = {v.x, v.y, v.z, v.w};
    bf16x4 h, l;
#pragma unroll
    for (int e = 0; e < 4; e++) {
        bf16 hh = (bf16)vv[e];
        h[e] = hh;
        l[e] = (bf16)(vv[e] - (float)hh);
    }
    *(bf16x4*)(hi + (size_t)t4 * 4) = h;
    *(bf16x4*)(lo + (size_t)t4 * 4) = l;
}

// inv[s][v] = last j with out_idx[s][j]==v, else -1 (numpy last-dup-wins)
__global__ void inv_kernel(const int* __restrict__ out_idx, int* __restrict__ inv) {
    int t = blockIdx.x * blockDim.x + threadIdx.x;
    if (t >= NS * V_) return;
    int s = t >> 6, v = t & 63;
    int jf = -1;
#pragma unroll
    for (int j = 0; j < NO; j++)
        if (out_idx[(s << 5) | j] == v) jf = j;
    inv[t] = jf;
}

__device__ __forceinline__ float fast_tanh(float z) {
    float e = __expf(2.0f * z);
    return 1.0f - 2.0f / (e + 1.0f);
}

// x fragment-order address for element (batch row n, k = t*16 + q*4):
__device__ __forceinline__ int xaddr(int t, int q, int n) {
    return ((t >> 1) * 512) + (((t & 1) * 2 + (q >> 1)) * 128) + n * 8 + (q & 1) * 4;
}

// ---------------------------------------------------------------------------
// Persistent per-block recurrence, 256 blocks x 16 waves, 1 block/CU.
// Weight pipeline: 18 asm global_load_dwordx4 per wave per step, each pair
// reissued right after its consumption -> issue-to-use = one full step.
// Consumption paced by s_waitcnt vmcnt(16) + sched_barrier(0).
// FIFO (steady state): queue/step = 16 W1 + 2 W2 + <=1 out-store = 19 ops;
// at slice-p wait, younger-than-target = 17 -> vmcnt(16) retires the pair.
//
// NEW (round 6): per-block K-slice ROTATION. Block-uniform rot =
// (blockIdx>>3)&7 rotates the GEMM1 slice visit order (weights AND x reads,
// prologue included), de-synchronizing the 32 lockstep CUs of an XCD so
// they don't all request the same 16 L2 lines in the same cycle. FIFO op
// count/order is unchanged; fp32 slice-sum order commutes (rounding noise).
// ---------------------------------------------------------------------------
__launch_bounds__(1024, 4)
__global__ void lalr_main(const float* __restrict__ latent0,
                          const float* __restrict__ b1,
                          const float* __restrict__ b2,
                          const int*   __restrict__ state_seq,
                          const int*   __restrict__ inv,
                          const bf16*  __restrict__ W1h, const bf16* __restrict__ W1l,
                          const bf16*  __restrict__ W2h, const bf16* __restrict__ W2l,
                          float* __restrict__ out) {
    __shared__ bf16  xh[2][4096];        // 16 KB
    __shared__ bf16  xl[2][4096];        // 16 KB
    __shared__ float Sp[2][8][16][36];   // 36 KB
    __shared__ float b1s[NS * NL];       // 64 KB
    __shared__ float b2s[NS * NO];       //  8 KB
    __shared__ int   invs[NS * V_];      // 16 KB
    __shared__ int   sseq[T_];           // 0.5 KB   total 160,256 B <= 160 KiB

    const int tid  = threadIdx.x;
    const int wave = tid >> 6;           // 0..15
    const int lane = tid & 63;
    const int n    = lane & 15;          // batch row
    const int q    = lane >> 4;          // quad
    const int r0   = blockIdx.x * RB;
    const int t2   = wave & 1;           // GEMM2 col-tile
    const int ks2  = wave >> 1;          // GEMM2 K-slice

    // Rotated slice offsets (bf16 elements; slice stride = 512 = 32k x 16col
    // fragment block). Block-uniform -> SGPRs.
    const int rot = (blockIdx.x >> 3) & 7;
    const int d0 = ((0 + rot) & 7) * 512;
    const int d1 = ((1 + rot) & 7) * 512;
    const int d2 = ((2 + rot) & 7) * 512;
    const int d3 = ((3 + rot) & 7) * 512;
    const int d4 = ((4 + rot) & 7) * 512;
    const int d5 = ((5 + rot) & 7) * 512;
    const int d6 = ((6 + rot) & 7) * 512;
    const int d7 = ((7 + rot) & 7) * 512;

    // ---- stage uniforms into LDS (prologue-only global traffic) ----
    for (int k = tid; k < NS * NL / 4; k += 1024)
        ((float4*)b1s)[k] = ((const float4*)b1)[k];
    if (tid < NS * NO / 4) ((float4*)b2s)[tid] = ((const float4*)b2)[tid];
    if (tid < NS * V_ / 4) ((int4*)invs)[tid] = ((const int4*)inv)[tid];
    if (tid < T_) sseq[tid] = state_seq[tid];

    // ---- init: latent0 -> x[0] fragments ----
    {
        float4 v = *(const float4*)(latent0 + (size_t)(r0 + n) * NL + wave * 16 + q * 4);
        float vv[4] = {v.x, v.y, v.z, v.w};
        bf16x4 hv, lv;
#pragma unroll
        for (int e = 0; e < 4; e++) {
            bf16 hh = (bf16)vv[e];
            hv[e] = hh;
            lv[e] = (bf16)(vv[e] - (float)hh);
        }
        const int a = xaddr(wave, q, n);
        *(bf16x4*)(&xh[0][a]) = hv;
        *(bf16x4*)(&xl[0][a]) = lv;
    }

    int s0 = state_seq[0], s1 = -1, s2 = -1;

    // 18 loop-carried weight fragment registers (unified VGPR/AGPR file).
    bf16x8 pwh0, pwh1, pwh2, pwh3, pwh4, pwh5, pwh6, pwh7;
    bf16x8 pwl0, pwl1, pwl2, pwl3, pwl4, pwl5, pwl6, pwl7;
    bf16x8 w2h2, w2l2;

    const size_t wfrag = (size_t)wave * 8 * 512 + lane * 8;  // per-wave/lane W1 offset

    // Prologue issue of L_0 in exact (rotated) consumption order, 18 ops.
    {
        const bf16* h0 = W1h + (size_t)s0 * 16 * 8 * 512 + wfrag;
        const bf16* l0 = W1l + (size_t)s0 * 16 * 8 * 512 + wfrag;
        GLOAD(pwh0, h0 + d0); GLOAD(pwl0, l0 + d0);
        GLOAD(pwh1, h0 + d1); GLOAD(pwl1, l0 + d1);
        GLOAD(pwh2, h0 + d2); GLOAD(pwl2, l0 + d2);
        GLOAD(pwh3, h0 + d3); GLOAD(pwl3, l0 + d3);
        GLOAD(pwh4, h0 + d4); GLOAD(pwl4, l0 + d4);
        GLOAD(pwh5, h0 + d5); GLOAD(pwl5, l0 + d5);
        GLOAD(pwh6, h0 + d6); GLOAD(pwl6, l0 + d6);
        GLOAD(pwh7, h0 + d7); GLOAD(pwl7, l0 + d7);
        const bf16* c2h = W2h + (size_t)((s0 * 2 + t2) * 8 + ks2) * 512 + lane * 8;
        const bf16* c2l = W2l + (size_t)((s0 * 2 + t2) * 8 + ks2) * 512 + lane * 8;
        GLOAD(w2h2, c2h);     GLOAD(w2l2, c2l);   // placeholder (iter-0 GEMM2 skipped)
    }

    LGKM_BARRIER();      // x[0]/staging visible; weight loads stay in flight

// One GEMM1 slice (physical slice offset dks): LDS x reads, counted wait,
// fence, 3 MFMA, reissue the pair for next step at the same physical slice.
#define G1S(ks, dks) {                                                      \
        bf16x8 xa = *(const bf16x8*)(&xh[cur][dks + lane * 8]);             \
        bf16x8 xb = *(const bf16x8*)(&xl[cur][dks + lane * 8]);             \
        asm volatile("s_waitcnt vmcnt(16)" ::: "memory");                   \
        __builtin_amdgcn_sched_barrier(0);                                  \
        acc1 = MF(pwh##ks, xa, acc1);                                       \
        acc1 = MF(pwl##ks, xa, acc1);                                       \
        acc1 = MF(pwh##ks, xb, acc1);                                       \
        GLOAD(pwh##ks, nh0 + dks);                                          \
        GLOAD(pwl##ks, nl0 + dks);                                          \
    }

    for (int i = 0; i <= T_ + 1; i++) {
        const int ib  = i & 1;
        const int cur = ib;

        // next-step W1 base pointers (dummy state 0 in tail keeps FIFO shape)
        const int ns0 = (i + 1 < T_) ? sseq[i + 1] : -1;
        const int ls  = (ns0 >= 0) ? ns0 : 0;
        const bf16* nh0 = W1h + (size_t)ls * 16 * 8 * 512 + wfrag;
        const bf16* nl0 = W1l + (size_t)ls * 16 * 8 * 512 + wfrag;

        // ---- GEMM1 (state s0): full K=256, vmcnt-paced, rotated slices ----
        f32x4 acc1;
        if (s0 >= 0) {
            acc1 = (f32x4){0.f, 0.f, 0.f, 0.f};
            G1S(0, d0)
            G1S(1, d1)
            G1S(2, d2)
            G1S(3, d3)
            G1S(4, d4)
            G1S(5, d5)
            G1S(6, d6)
            G1S(7, d7)
        }

        // ---- GEMM2 (state s1): task (t2, ks2) ----
        if (s1 >= 0) {
            bf16x8 xa = *(const bf16x8*)(&xh[cur][ks2 * 512 + lane * 8]);
            bf16x8 xb = *(const bf16x8*)(&xl[cur][ks2 * 512 + lane * 8]);
            if (s0 >= 0) {
                asm volatile("s_waitcnt vmcnt(16)" ::: "memory");
            } else {
                // tail: GEMM1 skipped -> 16 dummy W1 loads unconsumed ahead
                asm volatile("s_waitcnt vmcnt(0)" ::: "memory");
            }
            __builtin_amdgcn_sched_barrier(0);
            f32x4 a2 = (f32x4){0.f, 0.f, 0.f, 0.f};
            a2 = MF(w2h2, xa, a2);
            a2 = MF(w2l2, xa, a2);
            a2 = MF(w2h2, xb, a2);
            if (ks2 == 0) {
                float4 bb = *(const float4*)(&b2s[s1 * NO + t2 * 16 + q * 4]);
                a2[0] += bb.x; a2[1] += bb.y; a2[2] += bb.z; a2[3] += bb.w;
            }
            *(f32x4*)(&Sp[ib][ks2][n][t2 * 16 + q * 4]) = a2;
        }
        if (s0 >= 0) {   // reissue W2 pair for next iteration (state = current s0)
            const bf16* n2h = W2h + (size_t)((s0 * 2 + t2) * 8 + ks2) * 512 + lane * 8;
            const bf16* n2l = W2l + (size_t)((s0 * 2 + t2) * 8 + ks2) * 512 + lane * 8;
            GLOAD(w2h2, n2h);
            GLOAD(w2l2, n2l);
        }

        // ---- softmax + shfl-scatter + store for step i-2 (first 4 waves) ----
        if (s2 >= 0 && tid < 256) {
            const int r  = tid >> 4;
            const int j0 = tid & 15;
            const int pb = (i - 1) & 1;
            float v0 = 0.f, v1 = 0.f;
#pragma unroll
            for (int w = 0; w < 8; w++) {
                v0 += Sp[pb][w][r][j0];
                v1 += Sp[pb][w][r][j0 + 16];
            }
            float m = fmaxf(v0, v1);
#pragma unroll
            for (int d = 1; d < 16; d <<= 1) m = fmaxf(m, __shfl_xor(m, d));
            float e0 = __expf(v0 - m), e1 = __expf(v1 - m);
            float su = e0 + e1;
#pragma unroll
            for (int d = 1; d < 16; d <<= 1) su += __shfl_xor(su, d);
            float is = 1.0f / su;
            float p0 = e0 * is, p1 = e1 * is;
            const int gb = lane & 48;     // 16-lane group base
            int4 iv4 = *(const int4*)(&invs[s2 * V_ + j0 * 4]);
            int ivv[4] = {iv4.x, iv4.y, iv4.z, iv4.w};
            float o[4];
#pragma unroll
            for (int e = 0; e < 4; e++) {
                float ga = __shfl(p0, gb + (ivv[e] & 15));
                float gc = __shfl(p1, gb + (ivv[e] & 15));
                o[e] = (ivv[e] < 0) ? 0.f : ((ivv[e] < 16) ? ga : gc);
            }
            *(float4*)(out + ((size_t)(r0 + r) * T_ + (i - 2)) * V_ + j0 * 4) = *(float4*)o;
        }

        // ---- tanh + hi/lo split -> x[cur^1] ----
        if (s0 >= 0) {
            float4 bb = *(const float4*)(&b1s[s0 * NL + wave * 16 + q * 4]);
            float bv[4] = {bb.x, bb.y, bb.z, bb.w};
            bf16x4 hv, lv;
#pragma unroll
            for (int e = 0; e < 4; e++) {
                float h = fast_tanh(acc1[e] + bv[e]);
                bf16 hh = (bf16)h;
                hv[e] = hh;
                lv[e] = (bf16)(h - (float)hh);
            }
            const int a = xaddr(wave, q, n);
            *(bf16x4*)(&xh[cur ^ 1][a]) = hv;
            *(bf16x4*)(&xl[cur ^ 1][a]) = lv;
        }

        s2 = s1; s1 = s0; s0 = ns0;
        LGKM_BARRIER();
    }
#undef G1S
}

extern "C" void kernel_launch(void* const* d_in, const int* in_sizes, int n_in,
                              void* d_out, int out_size, void* d_ws, size_t ws_size,
                              hipStream_t stream) {
    const float* latent0   = (const float*)d_in[0];
    const float* W1        = (const float*)d_in[1];
    const float* b1        = (const float*)d_in[2];
    const float* W2        = (const float*)d_in[3];
    const float* b2        = (const float*)d_in[4];
    const int*   state_seq = (const int*)d_in[5];
    const int*   out_idx   = (const int*)d_in[6];
    float* out = (float*)d_out;

    bf16* W1h = (bf16*)d_ws;
    bf16* W1l = W1h + (size_t)NS * NL * NL;
    bf16* W2h = W1l + (size_t)NS * NL * NL;
    bf16* W2l = W2h + (size_t)NS * NO * NL;
    int*  inv = (int*)(W2l + (size_t)NS * NO * NL);

    const int n4_w1 = NS * NL * NL / 4;   // 1,048,576
    const int n4_w2 = NS * NO * NL / 4;   // 131,072
    split_w_frag<4><<<n4_w1 / 256, 256, 0, stream>>>(W1, W1h, W1l, n4_w1);
    split_w_frag<1><<<n4_w2 / 256, 256, 0, stream>>>(W2, W2h, W2l, n4_w2);
    inv_kernel<<<(NS * V_ + 255) / 256, 256, 0, stream>>>(out_idx, inv);

    lalr_main<<<NBLK, 1024, 0, stream>>>(latent0, b1, b2, state_seq, inv,
                                         W1h, W1l, W2h, W2l, out);
}